// Round 15
// baseline (253.428 us; speedup 1.0000x reference)
//
#include <hip/hip_runtime.h>
#include <hip/hip_fp16.h>

typedef short short8 __attribute__((ext_vector_type(8)));
typedef float floatx4 __attribute__((ext_vector_type(4)));

#define NBATCH 2
#define SEQ 8192
#define DIM 1024
#define QKVLD 3072
#define NBUCK 128
#define MROWS 16384
#define QK_SCALE 0.35355339059327379f

#define MFMA16(a, b, c) __builtin_amdgcn_mfma_f32_16x16x32_bf16(a, b, c, 0, 0, 0)

static __device__ __forceinline__ unsigned short f2b(float f) {
  unsigned int u = __float_as_uint(f);
  u = (u + 0x7fffu + ((u >> 16) & 1u)) >> 16;
  return (unsigned short)u;
}
static __device__ __forceinline__ float b2f(unsigned short h) {
  return __uint_as_float(((unsigned int)h) << 16);
}

__device__ __forceinline__ void gload_lds16(const void* g, void* l) {
  __builtin_amdgcn_global_load_lds(
      (const __attribute__((address_space(1))) unsigned int*)g,
      (__attribute__((address_space(3))) unsigned int*)l, 16, 0, 0);
}

__global__ void ws_sentinel(float* out, float v) { out[0] = v; }

static __device__ __forceinline__ ushort4 cast_u4(float4 v) {
  ushort4 h; h.x = f2b(v.x); h.y = f2b(v.y); h.z = f2b(v.z); h.w = f2b(v.w); return h;
}

// Fused prep: x, Wq/Wk/Wv (concat), Wo -> bf16 cast.
__global__ __launch_bounds__(256) void prep(
    const float4* __restrict__ x, const float4* __restrict__ Wq,
    const float4* __restrict__ Wk, const float4* __restrict__ Wv,
    const float4* __restrict__ Wo,
    ushort4* __restrict__ xb, ushort4* __restrict__ wchi, ushort4* __restrict__ wob)
{
  const int bid = blockIdx.x, t = threadIdx.x;
  if (bid < 4096) {
    for (int i = bid * 256 + t; i < MROWS * DIM / 4; i += 4096 * 256)
      xb[i] = cast_u4(x[i]);
  } else {
    const int r = bid - 4096;            // 0..1023
    const int m = r >> 8;                // matrix id
    const int base = (r & 255) * 256 + t;
    const int n4 = DIM * DIM / 4;        // 262144
    const float4* src = (m == 0) ? Wq : (m == 1 ? Wk : (m == 2 ? Wv : Wo));
    ushort4* dst = (m < 3) ? (wchi + (size_t)m * n4) : wob;
    for (int i = base; i < n4; i += 65536) dst[i] = cast_u4(src[i]);
  }
}

// Unified 256x256 GEMM, quad-buffered lookahead-2 + register fragment
// double-buffer. r14 lesson: without a fence the compiler SINKS the
// readfrags(next) ds_reads below the MFMA cluster to save 96 VGPRs
// (observed VGPR_Count=128 < the ~224 two-set minimum), re-serializing the
// read-phase/MFMA-phase convoy. The sched_barrier(0) between readfrags and
// the MFMA cluster pins the 12 ds_reads ABOVE the MFMAs; they have no
// consumer this iteration, so the LDS burst returns under the MFMA burst.
// Pipeline: stage(s+2) [buf (s+2)&3]; vmcnt(4)="tile s+1 landed"; barrier;
// readfrags(s+1); FENCE; 32 MFMA on frags(s). One barrier per step.
// WAR: stage(s+2) writes buf[(s+2)&3]; its prior readers drained >=2
// barriers earlier. Chunk-XOR LDS swizzle (T2), bijective XCD swizzle (T1),
// setprio (T5).
// EPI=1: bf16 epilogue -> {qb,kb,vb} (uniform per block since 1024%256==0).
// EPI=0: fp32 + bias -> C.
template <int EPI, int NCB, int K>
__global__ __launch_bounds__(512) void gemm256(
    const unsigned short* __restrict__ A, const unsigned short* __restrict__ B,
    unsigned short* __restrict__ qb, unsigned short* __restrict__ kb,
    unsigned short* __restrict__ vb,
    float* __restrict__ C, const float* __restrict__ bias)
{
  __shared__ unsigned short As[4][256 * 32];   // 4 x 16 KiB
  __shared__ unsigned short Bs[4][256 * 32];   // 4 x 16 KiB  (128 KiB total)
  const int t = threadIdx.x;
  const int l = t & 63, w = t >> 6;            // 8 waves
  const int wr = w >> 2, wc = w & 3;           // 2M x 4N wave grid
  const int bid0 = blockIdx.y * NCB + blockIdx.x;
  const int swz = (bid0 & 7) * (NCB * 8) + (bid0 >> 3);   // bijective, nwg%8==0
  const int m0 = (swz / NCB) * 256, n0 = (swz % NCB) * 256;
  const int lr = l & 15;
  const int lkx = (((l >> 4) ^ ((l >> 1) & 3))) * 8;   // swizzled chunk (shorts)
  constexpr int kt = K >> 5;

  auto stage = [&](int buf, int ks) {
#pragma unroll
    for (int j = 0; j < 2; ++j) {
      const int idx = j * 512 + t;
      const int row = idx >> 2, qc = idx & 3;  // 256 rows x 4 chunks of 8 shorts
      const int qcx = qc ^ ((row >> 1) & 3);   // pre-swizzled global chunk
      gload_lds16(A + (size_t)(m0 + row) * K + ks + qcx * 8, &As[buf][idx * 8]);
      gload_lds16(B + (size_t)(n0 + row) * K + ks + qcx * 8, &Bs[buf][idx * 8]);
    }
  };

  short8 fa[2][8], fb[2][4];
  auto readfrags = [&](int set, int buf) {
#pragma unroll
    for (int mi = 0; mi < 8; ++mi)
      fa[set][mi] = *(const short8*)&As[buf][(wr * 128 + mi * 16 + lr) * 32 + lkx];
#pragma unroll
    for (int ni = 0; ni < 4; ++ni)
      fb[set][ni] = *(const short8*)&Bs[buf][(wc * 64 + ni * 16 + lr) * 32 + lkx];
  };

  floatx4 acc[8][4] = {};
  stage(0, 0);
  stage(1, 32);
  asm volatile("s_waitcnt vmcnt(4)" ::: "memory");   // tile 0 landed
  __builtin_amdgcn_s_barrier();
  __builtin_amdgcn_sched_barrier(0);
  readfrags(0, 0);

#pragma unroll 2
  for (int s = 0; s < kt; ++s) {
    const int cur = s & 1;
    if (s + 2 < kt) stage((s + 2) & 3, (s + 2) << 5);
    if (s + 1 < kt) {
      if (s + 2 < kt) {
        asm volatile("s_waitcnt vmcnt(4)" ::: "memory");  // tile s+1 landed
      } else {
        asm volatile("s_waitcnt vmcnt(0)" ::: "memory");
      }
      __builtin_amdgcn_s_barrier();                       // visible to all waves
      __builtin_amdgcn_sched_barrier(0);
      readfrags(cur ^ 1, (s + 1) & 3);
      __builtin_amdgcn_sched_barrier(0);                  // PIN reads above MFMAs
    }
    __builtin_amdgcn_s_setprio(1);
#pragma unroll
    for (int mi = 0; mi < 8; ++mi)
#pragma unroll
      for (int ni = 0; ni < 4; ++ni)
        acc[mi][ni] = MFMA16(fa[cur][mi], fb[cur][ni], acc[mi][ni]);
    __builtin_amdgcn_s_setprio(0);
  }
#pragma unroll
  for (int mi = 0; mi < 8; ++mi)
#pragma unroll
    for (int ni = 0; ni < 4; ++ni)
#pragma unroll
      for (int i = 0; i < 4; ++i) {
        const int row = m0 + wr * 128 + mi * 16 + (l >> 4) * 4 + i;
        const int coff = wc * 64 + ni * 16 + lr;
        if (EPI == 0) {
          C[(size_t)row * DIM + n0 + coff] = acc[mi][ni][i] + bias[n0 + coff];
        } else {
          const int sel = n0 >> 10;                       // uniform per block
          unsigned short* dst = (sel == 0) ? qb : (sel == 1 ? kb : vb);
          dst[(size_t)row * DIM + (n0 & 1023) + coff] = f2b(acc[mi][ni][i]);
        }
      }
}

// Per-bucket: S[d][e] = sum_p psi(k)[p][d] * v[p][e] (fp16 out); ksum fp32.
__global__ __launch_bounds__(256) void bucket_stats(
    const unsigned short* __restrict__ kb, const unsigned short* __restrict__ vb,
    __half* __restrict__ S, float* __restrict__ ksum)
{
  const int bid = blockIdx.x;           // bh*128 + u
  const int u = bid & 127, bh = bid >> 7;
  const int b = bh >> 4, h = bh & 15;
  const int t = threadIdx.x;
  __shared__ float kps[64][64];
  __shared__ float vv[64][64];
  const size_t rowbase = ((size_t)b * SEQ + (size_t)u * 64) * DIM + h * 64;
  for (int idx = t; idx < 1024; idx += 256) {
    const int p = idx >> 4, d4 = (idx & 15) * 4;
    const size_t r = rowbase + (size_t)p * DIM + d4;
    const ushort4 kk = *(const ushort4*)&kb[r];
    const ushort4 vx = *(const ushort4*)&vb[r];
    const unsigned short ka[4] = {kk.x, kk.y, kk.z, kk.w};
    const unsigned short va[4] = {vx.x, vx.y, vx.z, vx.w};
#pragma unroll
    for (int j = 0; j < 4; ++j) {
      const float z = b2f(ka[j]) * QK_SCALE;
      kps[p][d4 + j] = z > 0.f ? z + 1.f : __expf(z);   // elu(z)+1
      vv[p][d4 + j] = b2f(va[j]);
    }
  }
  __syncthreads();
  const int e4 = (t & 15) * 4, d4 = (t >> 4) * 4;
  float a[4][4] = {};
  for (int p = 0; p < 64; ++p) {
    const float4 kv = *(const float4*)&kps[p][d4];
    const float4 vx = *(const float4*)&vv[p][e4];
    const float kk[4] = {kv.x, kv.y, kv.z, kv.w};
    const float vb2[4] = {vx.x, vx.y, vx.z, vx.w};
#pragma unroll
    for (int i = 0; i < 4; ++i)
#pragma unroll
      for (int j = 0; j < 4; ++j) a[i][j] += kk[i] * vb2[j];
  }
  const size_t sb = (size_t)bid * 4096;
  __half2* S2 = (__half2*)S;
#pragma unroll
  for (int i = 0; i < 4; ++i) {
    const size_t base2 = (sb + (size_t)(d4 + i) * 64 + e4) >> 1;
    S2[base2]     = __floats2half2_rn(a[i][0], a[i][1]);
    S2[base2 + 1] = __floats2half2_rn(a[i][2], a[i][3]);
  }
  if (t < 64) {
    float ssum = 0.f;
    for (int p = 0; p < 64; ++p) ssum += kps[p][t];
    ksum[(size_t)bid * 64 + t] = ssum;
  }
}

// Fused cumsum over buckets: S fp16 scalar chains (512 blocks) + ksum fp32.
__global__ void scan_all(__half* __restrict__ S, float* __restrict__ ks) {
  const int bid = blockIdx.x;
  if (bid < 512) {
    const int tid = bid * 256 + threadIdx.x;
    const int bh = tid >> 12, de = tid & 4095;
    __half* p = S + (size_t)bh * NBUCK * 4096 + de;
    float run = 0.f;
    for (int u = 0; u < NBUCK; ++u) {
      run += __half2float(p[(size_t)u * 4096]);
      p[(size_t)u * 4096] = __float2half_rn(run);
    }
  } else {
    const int tid = (bid - 512) * 256 + threadIdx.x;
    if (tid >= 2048) return;
    const int bh = tid >> 6, d = tid & 63;
    float* p = ks + (size_t)bh * NBUCK * 64 + d;
    float run = 0.f;
    for (int u = 0; u < NBUCK; ++u) { run += p[u * 64]; p[u * 64] = run; }
  }
}

// Per bucket u: attn = softmax(q*scale) @ (Ccum[u-1] / (kcum[u-1]+eps)); u=0 -> 0.
// Matmul remap: thread = 4 rows x 4 cols => 2 contiguous b128 LDS reads per d.
__global__ __launch_bounds__(256) void attn_out(
    const unsigned short* __restrict__ qb, const __half* __restrict__ S,
    const float* __restrict__ ks, unsigned short* __restrict__ ab)
{
  const int bid = blockIdx.x;
  const int u = bid & 127, bh = bid >> 7;
  const int b = bh >> 4, h = bh & 15;
  const int t = threadIdx.x, l = t & 63, w = t >> 6;
  if (u == 0) {
    const size_t orow = (size_t)b * SEQ + (size_t)w * 16;
#pragma unroll
    for (int i = 0; i < 16; ++i) ab[(orow + i) * DIM + h * 64 + l] = 0;
    return;
  }
  __shared__ float cc[64][64];
  __shared__ float qnT[64][68];
  __shared__ float recip[64];
  __shared__ float part[64][4];
  __shared__ float rowstat[64];
  const size_t sb = ((size_t)bh * NBUCK + (u - 1)) * 4096;
  const __half2* S2 = (const __half2*)(S + sb);
  for (int idx = t; idx < 2048; idx += 256) {
    const float2 v2 = __half22float2(S2[idx]);
    ((float*)cc)[idx * 2] = v2.x;
    ((float*)cc)[idx * 2 + 1] = v2.y;
  }
  if (t < 64) recip[t] = 1.f / (ks[((size_t)bh * NBUCK + (u - 1)) * 64 + t] + 1e-6f);
  const int p = t >> 2, c = t & 3;
  const size_t qrow = ((size_t)b * SEQ + (size_t)u * 64 + p) * DIM + h * 64 + c * 16;
  float qv[16];
#pragma unroll
  for (int ii = 0; ii < 4; ++ii) {
    const ushort4 qq = *(const ushort4*)&qb[qrow + ii * 4];
    qv[ii * 4 + 0] = b2f(qq.x) * QK_SCALE;
    qv[ii * 4 + 1] = b2f(qq.y) * QK_SCALE;
    qv[ii * 4 + 2] = b2f(qq.z) * QK_SCALE;
    qv[ii * 4 + 3] = b2f(qq.w) * QK_SCALE;
  }
  float mx = qv[0];
#pragma unroll
  for (int i = 1; i < 16; ++i) mx = fmaxf(mx, qv[i]);
  part[p][c] = mx;
  __syncthreads();
  if (c == 0) rowstat[p] = fmaxf(fmaxf(part[p][0], part[p][1]), fmaxf(part[p][2], part[p][3]));
  __syncthreads();
  const float rm = rowstat[p];
  float sum = 0.f;
#pragma unroll
  for (int i = 0; i < 16; ++i) { qv[i] = __expf(qv[i] - rm); sum += qv[i]; }
  part[p][c] = sum;
  __syncthreads();
  if (c == 0) rowstat[p] = part[p][0] + part[p][1] + part[p][2] + part[p][3];
  __syncthreads();
  const float inv = 1.f / rowstat[p];
#pragma unroll
  for (int i = 0; i < 16; ++i) qnT[c * 16 + i][p] = qv[i] * inv * recip[c * 16 + i];
  __syncthreads();
  // attn[r][e] = sum_d qnT[d][r] * cc[d][e]; thread: rows r0..r0+3, cols c0..c0+3
  const int r0 = (t & 15) * 4, c0 = (t >> 4) * 4;
  float acc[4][4] = {};
  for (int d = 0; d < 64; ++d) {
    const float4 qr = *(const float4*)&qnT[d][r0];
    const float4 cv = *(const float4*)&cc[d][c0];
    const float qa[4] = {qr.x, qr.y, qr.z, qr.w};
    const float ca[4] = {cv.x, cv.y, cv.z, cv.w};
#pragma unroll
    for (int i = 0; i < 4; ++i)
#pragma unroll
      for (int j = 0; j < 4; ++j) acc[i][j] += qa[i] * ca[j];
  }
  const size_t orow = (size_t)b * SEQ + (size_t)u * 64 + r0;
#pragma unroll
  for (int i = 0; i < 4; ++i) {
    ushort4 st;
    st.x = f2b(acc[i][0]); st.y = f2b(acc[i][1]);
    st.z = f2b(acc[i][2]); st.w = f2b(acc[i][3]);
    *(ushort4*)&ab[(orow + i) * DIM + h * 64 + c0] = st;
  }
}

extern "C" void kernel_launch(void* const* d_in, const int* in_sizes, int n_in,
                              void* d_out, int out_size, void* d_ws, size_t ws_size,
                              hipStream_t stream) {
  const float* x  = (const float*)d_in[0];
  const float* Wq = (const float*)d_in[1];
  const float* Wk = (const float*)d_in[2];
  const float* Wv = (const float*)d_in[3];
  const float* Wo = (const float*)d_in[4];
  const float* bo = (const float*)d_in[5];
  float* out = (float*)d_out;

  char* ws = (char*)d_ws;
  size_t off = 0;
  auto carve = [&](size_t bytes) -> void* {
    void* pp = ws + off;
    off += (bytes + 255) & ~(size_t)255;
    return pp;
  };
  unsigned short* qb = (unsigned short*)carve((size_t)MROWS * DIM * 2);   // 32 MiB
  unsigned short* kb = (unsigned short*)carve((size_t)MROWS * DIM * 2);   // 32 MiB (ab overlays)
  unsigned short* vb = (unsigned short*)carve((size_t)MROWS * DIM * 2);   // 32 MiB
  unsigned short* wob = (unsigned short*)carve((size_t)DIM * DIM * 2);    // 2 MiB
  float* ksum = (float*)carve((size_t)32 * NBUCK * 64 * 4);               // 1 MiB
  // 64 MiB scratch: phase1 = xb(32) + wchi(6); phase2+ = S fp16 (32, overlay on xb)
  char* scratch = (char*)carve((size_t)32 * NBUCK * 4096 * 4);
  unsigned short* xb   = (unsigned short*)scratch;
  unsigned short* wchi = (unsigned short*)(scratch + (size_t)MROWS * DIM * 2);
  __half* S = (__half*)scratch;
  unsigned short* ab = kb;  // overlay (kb dead after bucket_stats)
  if (off > ws_size) {
    ws_sentinel<<<1, 1, 0, stream>>>(out, (float)ws_size);
    return;
  }

  prep<<<5120, 256, 0, stream>>>((const float4*)x, (const float4*)Wq, (const float4*)Wk,
                                 (const float4*)Wv, (const float4*)Wo,
                                 (ushort4*)xb, (ushort4*)wchi, (ushort4*)wob);
  gemm256<1, 12, DIM><<<dim3(12, 64), 512, 0, stream>>>(
      xb, wchi, qb, kb, vb, nullptr, nullptr);
  bucket_stats<<<4096, 256, 0, stream>>>(kb, vb, S, ksum);
  scan_all<<<520, 256, 0, stream>>>(S, ksum);
  attn_out<<<4096, 256, 0, stream>>>(qb, S, ksum, ab);
  gemm256<0, 4, DIM><<<dim3(4, 64), 512, 0, stream>>>(
      ab, wob, nullptr, nullptr, nullptr, out, bo);
}

// Round 16
// 235.857 us; speedup vs baseline: 1.0745x; 1.0745x over previous
//
#include <hip/hip_runtime.h>
#include <hip/hip_fp16.h>

typedef short short8 __attribute__((ext_vector_type(8)));
typedef float floatx4 __attribute__((ext_vector_type(4)));

#define NBATCH 2
#define SEQ 8192
#define DIM 1024
#define QKVLD 3072
#define NBUCK 128
#define MROWS 16384
#define QK_SCALE 0.35355339059327379f

#define MFMA16(a, b, c) __builtin_amdgcn_mfma_f32_16x16x32_bf16(a, b, c, 0, 0, 0)

static __device__ __forceinline__ unsigned short f2b(float f) {
  unsigned int u = __float_as_uint(f);
  u = (u + 0x7fffu + ((u >> 16) & 1u)) >> 16;
  return (unsigned short)u;
}
static __device__ __forceinline__ float b2f(unsigned short h) {
  return __uint_as_float(((unsigned int)h) << 16);
}

__device__ __forceinline__ void gload_lds16(const void* g, void* l) {
  __builtin_amdgcn_global_load_lds(
      (const __attribute__((address_space(1))) unsigned int*)g,
      (__attribute__((address_space(3))) unsigned int*)l, 16, 0, 0);
}

__global__ void ws_sentinel(float* out, float v) { out[0] = v; }

static __device__ __forceinline__ ushort4 cast_u4(float4 v) {
  ushort4 h; h.x = f2b(v.x); h.y = f2b(v.y); h.z = f2b(v.z); h.w = f2b(v.w); return h;
}

// Fused prep: x, Wq/Wk/Wv (concat), Wo -> bf16 cast.
__global__ __launch_bounds__(256) void prep(
    const float4* __restrict__ x, const float4* __restrict__ Wq,
    const float4* __restrict__ Wk, const float4* __restrict__ Wv,
    const float4* __restrict__ Wo,
    ushort4* __restrict__ xb, ushort4* __restrict__ wchi, ushort4* __restrict__ wob)
{
  const int bid = blockIdx.x, t = threadIdx.x;
  if (bid < 4096) {
    for (int i = bid * 256 + t; i < MROWS * DIM / 4; i += 4096 * 256)
      xb[i] = cast_u4(x[i]);
  } else {
    const int r = bid - 4096;            // 0..1023
    const int m = r >> 8;                // matrix id
    const int base = (r & 255) * 256 + t;
    const int n4 = DIM * DIM / 4;        // 262144
    const float4* src = (m == 0) ? Wq : (m == 1 ? Wk : (m == 2 ? Wv : Wo));
    ushort4* dst = (m < 3) ? (wchi + (size_t)m * n4) : wob;
    for (int i = base; i < n4; i += 65536) dst[i] = cast_u4(src[i]);
  }
}

// Unified 256x256 GEMM (r12/r15 schedule, frozen — 106us qkv, MfmaUtil 43%).
template <int EPI, int NCB, int K>
__global__ __launch_bounds__(512) void gemm256(
    const unsigned short* __restrict__ A, const unsigned short* __restrict__ B,
    unsigned short* __restrict__ qb, unsigned short* __restrict__ kb,
    unsigned short* __restrict__ vb,
    float* __restrict__ C, const float* __restrict__ bias)
{
  __shared__ unsigned short As[4][256 * 32];   // 4 x 16 KiB
  __shared__ unsigned short Bs[4][256 * 32];   // 4 x 16 KiB  (128 KiB total)
  const int t = threadIdx.x;
  const int l = t & 63, w = t >> 6;            // 8 waves
  const int wr = w >> 2, wc = w & 3;           // 2M x 4N wave grid
  const int bid0 = blockIdx.y * NCB + blockIdx.x;
  const int swz = (bid0 & 7) * (NCB * 8) + (bid0 >> 3);   // bijective, nwg%8==0
  const int m0 = (swz / NCB) * 256, n0 = (swz % NCB) * 256;
  const int lr = l & 15;
  const int lkx = (((l >> 4) ^ ((l >> 1) & 3))) * 8;   // swizzled chunk (shorts)
  constexpr int kt = K >> 5;

  auto stage = [&](int buf, int ks) {
#pragma unroll
    for (int j = 0; j < 2; ++j) {
      const int idx = j * 512 + t;
      const int row = idx >> 2, qc = idx & 3;  // 256 rows x 4 chunks of 8 shorts
      const int qcx = qc ^ ((row >> 1) & 3);   // pre-swizzled global chunk
      gload_lds16(A + (size_t)(m0 + row) * K + ks + qcx * 8, &As[buf][idx * 8]);
      gload_lds16(B + (size_t)(n0 + row) * K + ks + qcx * 8, &Bs[buf][idx * 8]);
    }
  };

  short8 fa[2][8], fb[2][4];
  auto readfrags = [&](int set, int buf) {
#pragma unroll
    for (int mi = 0; mi < 8; ++mi)
      fa[set][mi] = *(const short8*)&As[buf][(wr * 128 + mi * 16 + lr) * 32 + lkx];
#pragma unroll
    for (int ni = 0; ni < 4; ++ni)
      fb[set][ni] = *(const short8*)&Bs[buf][(wc * 64 + ni * 16 + lr) * 32 + lkx];
  };

  floatx4 acc[8][4] = {};
  stage(0, 0);
  stage(1, 32);
  asm volatile("s_waitcnt vmcnt(4)" ::: "memory");   // tile 0 landed
  __builtin_amdgcn_s_barrier();
  __builtin_amdgcn_sched_barrier(0);
  readfrags(0, 0);

#pragma unroll 2
  for (int s = 0; s < kt; ++s) {
    const int cur = s & 1;
    if (s + 2 < kt) stage((s + 2) & 3, (s + 2) << 5);
    if (s + 1 < kt) {
      if (s + 2 < kt) {
        asm volatile("s_waitcnt vmcnt(4)" ::: "memory");  // tile s+1 landed
      } else {
        asm volatile("s_waitcnt vmcnt(0)" ::: "memory");
      }
      __builtin_amdgcn_s_barrier();                       // visible to all waves
      __builtin_amdgcn_sched_barrier(0);
      readfrags(cur ^ 1, (s + 1) & 3);
      __builtin_amdgcn_sched_barrier(0);                  // pin reads above MFMAs
    }
    __builtin_amdgcn_s_setprio(1);
#pragma unroll
    for (int mi = 0; mi < 8; ++mi)
#pragma unroll
      for (int ni = 0; ni < 4; ++ni)
        acc[mi][ni] = MFMA16(fa[cur][mi], fb[cur][ni], acc[mi][ni]);
    __builtin_amdgcn_s_setprio(0);
  }
#pragma unroll
  for (int mi = 0; mi < 8; ++mi)
#pragma unroll
    for (int ni = 0; ni < 4; ++ni)
#pragma unroll
      for (int i = 0; i < 4; ++i) {
        const int row = m0 + wr * 128 + mi * 16 + (l >> 4) * 4 + i;
        const int coff = wc * 64 + ni * 16 + lr;
        if (EPI == 0) {
          C[(size_t)row * DIM + n0 + coff] = acc[mi][ni][i] + bias[n0 + coff];
        } else {
          const int sel = n0 >> 10;                       // uniform per block
          unsigned short* dst = (sel == 0) ? qb : (sel == 1 ? kb : vb);
          dst[(size_t)row * DIM + (n0 & 1023) + coff] = f2b(acc[mi][ni][i]);
        }
      }
}

// Per-bucket MFMA rewrite: S[d][e] = sum_p psi(k)[p][d]*v[p][e] as a 64x64x64
// bf16 MFMA matmul (was VALU: 2.1GB LDS reads/launch). psi(k) and v are staged
// TRANSPOSED into bf16 LDS ([d][p] / [e][p], pad 72 shorts = 9x16B rows) so the
// contraction dim p is row-contiguous for both MFMA operands. psi rounds to
// bf16 (~0.2% on S; ksum uses the SAME rounded psi, so the context/ksum ratio
// error partially cancels). 4 waves x 1 row-tile x 4 col-tiles x K=64.
__global__ __launch_bounds__(256) void bucket_stats(
    const unsigned short* __restrict__ kb, const unsigned short* __restrict__ vb,
    __half* __restrict__ S, float* __restrict__ ksum)
{
  const int bid = blockIdx.x;           // bh*128 + u
  const int u = bid & 127, bh = bid >> 7;
  const int b = bh >> 4, h = bh & 15;
  const int t = threadIdx.x, l = t & 63, w = t >> 6;
  __shared__ unsigned short kT[64][72];  // psi(k) bf16, [d][p]
  __shared__ unsigned short vT[64][72];  // v bf16, [e][p]
  const size_t rowbase = ((size_t)b * SEQ + (size_t)u * 64) * DIM + h * 64;
  {
    const int p = t >> 2, d0 = (t & 3) * 16;
    const size_t r = rowbase + (size_t)p * DIM + d0;
    const short8 k0 = *(const short8*)&kb[r];
    const short8 k1 = *(const short8*)&kb[r + 8];
    const short8 v0 = *(const short8*)&vb[r];
    const short8 v1 = *(const short8*)&vb[r + 8];
#pragma unroll
    for (int j = 0; j < 8; ++j) {
      const float z0 = b2f((unsigned short)k0[j]) * QK_SCALE;
      const float z1 = b2f((unsigned short)k1[j]) * QK_SCALE;
      kT[d0 + j][p]     = f2b(z0 > 0.f ? z0 + 1.f : __expf(z0));
      kT[d0 + 8 + j][p] = f2b(z1 > 0.f ? z1 + 1.f : __expf(z1));
      vT[d0 + j][p]     = (unsigned short)v0[j];
      vT[d0 + 8 + j][p] = (unsigned short)v1[j];
    }
  }
  __syncthreads();
  const int lr = l & 15, lk = (l >> 4) * 8;
  const short8 a0 = *(const short8*)&kT[w * 16 + lr][lk];
  const short8 a1 = *(const short8*)&kT[w * 16 + lr][lk + 32];
  floatx4 acc[4] = {};
#pragma unroll
  for (int ni = 0; ni < 4; ++ni) {
    const short8 b0 = *(const short8*)&vT[ni * 16 + lr][lk];
    const short8 b1 = *(const short8*)&vT[ni * 16 + lr][lk + 32];
    acc[ni] = MFMA16(a0, b0, acc[ni]);
    acc[ni] = MFMA16(a1, b1, acc[ni]);
  }
  const size_t sb = (size_t)bid * 4096;
#pragma unroll
  for (int ni = 0; ni < 4; ++ni)
#pragma unroll
    for (int i = 0; i < 4; ++i) {
      const int d = w * 16 + (l >> 4) * 4 + i;   // C/D: row=(lane>>4)*4+reg
      const int e = ni * 16 + lr;                // C/D: col=lane&15
      S[sb + d * 64 + e] = __float2half_rn(acc[ni][i]);
    }
  __syncthreads();
  if (t < 64) {
    float ssum = 0.f;
    for (int p = 0; p < 64; ++p) ssum += b2f(kT[t][p]);
    ksum[(size_t)bid * 64 + t] = ssum;
  }
}

// Fused cumsum over buckets. Latency fix: the 128-long chains issue loads in
// batches of 8 (independent addresses -> 8 in flight) before the serial
// accumulate+store; summation order is bitwise identical to the scalar loop.
__global__ void scan_all(__half* __restrict__ S, float* __restrict__ ks) {
  const int bid = blockIdx.x;
  if (bid < 512) {
    const int tid = bid * 256 + threadIdx.x;
    const int bh = tid >> 12, de = tid & 4095;
    __half* p = S + (size_t)bh * NBUCK * 4096 + de;
    float run = 0.f;
    for (int u0 = 0; u0 < NBUCK; u0 += 8) {
      __half v[8];
#pragma unroll
      for (int j = 0; j < 8; ++j) v[j] = p[(size_t)(u0 + j) * 4096];
#pragma unroll
      for (int j = 0; j < 8; ++j) {
        run += __half2float(v[j]);
        v[j] = __float2half_rn(run);
      }
#pragma unroll
      for (int j = 0; j < 8; ++j) p[(size_t)(u0 + j) * 4096] = v[j];
    }
  } else {
    const int tid = (bid - 512) * 256 + threadIdx.x;
    if (tid >= 2048) return;
    const int bh = tid >> 6, d = tid & 63;
    float* p = ks + (size_t)bh * NBUCK * 64 + d;
    float run = 0.f;
    for (int u0 = 0; u0 < NBUCK; u0 += 8) {
      float v[8];
#pragma unroll
      for (int j = 0; j < 8; ++j) v[j] = p[(u0 + j) * 64];
#pragma unroll
      for (int j = 0; j < 8; ++j) { run += v[j]; v[j] = run; }
#pragma unroll
      for (int j = 0; j < 8; ++j) p[(u0 + j) * 64] = v[j];
    }
  }
}

// Per bucket u: attn = softmax(q*scale) @ (Ccum[u-1] / (kcum[u-1]+eps)); u=0 -> 0.
// Matmul remap: thread = 4 rows x 4 cols => 2 contiguous b128 LDS reads per d.
__global__ __launch_bounds__(256) void attn_out(
    const unsigned short* __restrict__ qb, const __half* __restrict__ S,
    const float* __restrict__ ks, unsigned short* __restrict__ ab)
{
  const int bid = blockIdx.x;
  const int u = bid & 127, bh = bid >> 7;
  const int b = bh >> 4, h = bh & 15;
  const int t = threadIdx.x, l = t & 63, w = t >> 6;
  if (u == 0) {
    const size_t orow = (size_t)b * SEQ + (size_t)w * 16;
#pragma unroll
    for (int i = 0; i < 16; ++i) ab[(orow + i) * DIM + h * 64 + l] = 0;
    return;
  }
  __shared__ float cc[64][64];
  __shared__ float qnT[64][68];
  __shared__ float recip[64];
  __shared__ float part[64][4];
  __shared__ float rowstat[64];
  const size_t sb = ((size_t)bh * NBUCK + (u - 1)) * 4096;
  const __half2* S2 = (const __half2*)(S + sb);
  for (int idx = t; idx < 2048; idx += 256) {
    const float2 v2 = __half22float2(S2[idx]);
    ((float*)cc)[idx * 2] = v2.x;
    ((float*)cc)[idx * 2 + 1] = v2.y;
  }
  if (t < 64) recip[t] = 1.f / (ks[((size_t)bh * NBUCK + (u - 1)) * 64 + t] + 1e-6f);
  const int p = t >> 2, c = t & 3;
  const size_t qrow = ((size_t)b * SEQ + (size_t)u * 64 + p) * DIM + h * 64 + c * 16;
  float qv[16];
#pragma unroll
  for (int ii = 0; ii < 4; ++ii) {
    const ushort4 qq = *(const ushort4*)&qb[qrow + ii * 4];
    qv[ii * 4 + 0] = b2f(qq.x) * QK_SCALE;
    qv[ii * 4 + 1] = b2f(qq.y) * QK_SCALE;
    qv[ii * 4 + 2] = b2f(qq.z) * QK_SCALE;
    qv[ii * 4 + 3] = b2f(qq.w) * QK_SCALE;
  }
  float mx = qv[0];
#pragma unroll
  for (int i = 1; i < 16; ++i) mx = fmaxf(mx, qv[i]);
  part[p][c] = mx;
  __syncthreads();
  if (c == 0) rowstat[p] = fmaxf(fmaxf(part[p][0], part[p][1]), fmaxf(part[p][2], part[p][3]));
  __syncthreads();
  const float rm = rowstat[p];
  float sum = 0.f;
#pragma unroll
  for (int i = 0; i < 16; ++i) { qv[i] = __expf(qv[i] - rm); sum += qv[i]; }
  part[p][c] = sum;
  __syncthreads();
  if (c == 0) rowstat[p] = part[p][0] + part[p][1] + part[p][2] + part[p][3];
  __syncthreads();
  const float inv = 1.f / rowstat[p];
#pragma unroll
  for (int i = 0; i < 16; ++i) qnT[c * 16 + i][p] = qv[i] * inv * recip[c * 16 + i];
  __syncthreads();
  // attn[r][e] = sum_d qnT[d][r] * cc[d][e]; thread: rows r0..r0+3, cols c0..c0+3
  const int r0 = (t & 15) * 4, c0 = (t >> 4) * 4;
  float acc[4][4] = {};
  for (int d = 0; d < 64; ++d) {
    const float4 qr = *(const float4*)&qnT[d][r0];
    const float4 cv = *(const float4*)&cc[d][c0];
    const float qa[4] = {qr.x, qr.y, qr.z, qr.w};
    const float ca[4] = {cv.x, cv.y, cv.z, cv.w};
#pragma unroll
    for (int i = 0; i < 4; ++i)
#pragma unroll
      for (int j = 0; j < 4; ++j) acc[i][j] += qa[i] * ca[j];
  }
  const size_t orow = (size_t)b * SEQ + (size_t)u * 64 + r0;
#pragma unroll
  for (int i = 0; i < 4; ++i) {
    ushort4 st;
    st.x = f2b(acc[i][0]); st.y = f2b(acc[i][1]);
    st.z = f2b(acc[i][2]); st.w = f2b(acc[i][3]);
    *(ushort4*)&ab[(orow + i) * DIM + h * 64 + c0] = st;
  }
}

extern "C" void kernel_launch(void* const* d_in, const int* in_sizes, int n_in,
                              void* d_out, int out_size, void* d_ws, size_t ws_size,
                              hipStream_t stream) {
  const float* x  = (const float*)d_in[0];
  const float* Wq = (const float*)d_in[1];
  const float* Wk = (const float*)d_in[2];
  const float* Wv = (const float*)d_in[3];
  const float* Wo = (const float*)d_in[4];
  const float* bo = (const float*)d_in[5];
  float* out = (float*)d_out;

  char* ws = (char*)d_ws;
  size_t off = 0;
  auto carve = [&](size_t bytes) -> void* {
    void* pp = ws + off;
    off += (bytes + 255) & ~(size_t)255;
    return pp;
  };
  unsigned short* qb = (unsigned short*)carve((size_t)MROWS * DIM * 2);   // 32 MiB
  unsigned short* kb = (unsigned short*)carve((size_t)MROWS * DIM * 2);   // 32 MiB (ab overlays)
  unsigned short* vb = (unsigned short*)carve((size_t)MROWS * DIM * 2);   // 32 MiB
  unsigned short* wob = (unsigned short*)carve((size_t)DIM * DIM * 2);    // 2 MiB
  float* ksum = (float*)carve((size_t)32 * NBUCK * 64 * 4);               // 1 MiB
  // 64 MiB scratch: phase1 = xb(32) + wchi(6); phase2+ = S fp16 (32, overlay on xb)
  char* scratch = (char*)carve((size_t)32 * NBUCK * 4096 * 4);
  unsigned short* xb   = (unsigned short*)scratch;
  unsigned short* wchi = (unsigned short*)(scratch + (size_t)MROWS * DIM * 2);
  __half* S = (__half*)scratch;
  unsigned short* ab = kb;  // overlay (kb dead after bucket_stats)
  if (off > ws_size) {
    ws_sentinel<<<1, 1, 0, stream>>>(out, (float)ws_size);
    return;
  }

  prep<<<5120, 256, 0, stream>>>((const float4*)x, (const float4*)Wq, (const float4*)Wk,
                                 (const float4*)Wv, (const float4*)Wo,
                                 (ushort4*)xb, (ushort4*)wchi, (ushort4*)wob);
  gemm256<1, 12, DIM><<<dim3(12, 64), 512, 0, stream>>>(
      xb, wchi, qb, kb, vb, nullptr, nullptr);
  bucket_stats<<<4096, 256, 0, stream>>>(kb, vb, S, ksum);
  scan_all<<<520, 256, 0, stream>>>(S, ksum);
  attn_out<<<4096, 256, 0, stream>>>(qb, S, ksum, ab);
  gemm256<0, 4, DIM><<<dim3(4, 64), 512, 0, stream>>>(
      ab, wob, nullptr, nullptr, nullptr, out, bo);
}

// Round 17
// 220.880 us; speedup vs baseline: 1.1474x; 1.0678x over previous
//
#include <hip/hip_runtime.h>
#include <hip/hip_fp16.h>

typedef short short8 __attribute__((ext_vector_type(8)));
typedef float floatx4 __attribute__((ext_vector_type(4)));

#define NBATCH 2
#define SEQ 8192
#define DIM 1024
#define QKVLD 3072
#define NBUCK 128
#define MROWS 16384
#define QK_SCALE 0.35355339059327379f

#define MFMA16(a, b, c) __builtin_amdgcn_mfma_f32_16x16x32_bf16(a, b, c, 0, 0, 0)

static __device__ __forceinline__ unsigned short f2b(float f) {
  unsigned int u = __float_as_uint(f);
  u = (u + 0x7fffu + ((u >> 16) & 1u)) >> 16;
  return (unsigned short)u;
}
static __device__ __forceinline__ float b2f(unsigned short h) {
  return __uint_as_float(((unsigned int)h) << 16);
}

__device__ __forceinline__ void gload_lds16(const void* g, void* l) {
  __builtin_amdgcn_global_load_lds(
      (const __attribute__((address_space(1))) unsigned int*)g,
      (__attribute__((address_space(3))) unsigned int*)l, 16, 0, 0);
}

__global__ void ws_sentinel(float* out, float v) { out[0] = v; }

static __device__ __forceinline__ ushort4 cast_u4(float4 v) {
  ushort4 h; h.x = f2b(v.x); h.y = f2b(v.y); h.z = f2b(v.z); h.w = f2b(v.w); return h;
}

// Fused prep: x, Wq/Wk/Wv (concat), Wo -> bf16 cast.
__global__ __launch_bounds__(256) void prep(
    const float4* __restrict__ x, const float4* __restrict__ Wq,
    const float4* __restrict__ Wk, const float4* __restrict__ Wv,
    const float4* __restrict__ Wo,
    ushort4* __restrict__ xb, ushort4* __restrict__ wchi, ushort4* __restrict__ wob)
{
  const int bid = blockIdx.x, t = threadIdx.x;
  if (bid < 4096) {
    for (int i = bid * 256 + t; i < MROWS * DIM / 4; i += 4096 * 256)
      xb[i] = cast_u4(x[i]);
  } else {
    const int r = bid - 4096;            // 0..1023
    const int m = r >> 8;                // matrix id
    const int base = (r & 255) * 256 + t;
    const int n4 = DIM * DIM / 4;        // 262144
    const float4* src = (m == 0) ? Wq : (m == 1 ? Wk : (m == 2 ? Wv : Wo));
    ushort4* dst = (m < 3) ? (wchi + (size_t)m * n4) : wob;
    for (int i = base; i < n4; i += 65536) dst[i] = cast_u4(src[i]);
  }
}

// Unified 256x256 GEMM (r12/r15 schedule, frozen — 106us qkv, MfmaUtil 43%).
template <int EPI, int NCB, int K>
__global__ __launch_bounds__(512) void gemm256(
    const unsigned short* __restrict__ A, const unsigned short* __restrict__ B,
    unsigned short* __restrict__ qb, unsigned short* __restrict__ kb,
    unsigned short* __restrict__ vb,
    float* __restrict__ C, const float* __restrict__ bias)
{
  __shared__ unsigned short As[4][256 * 32];   // 4 x 16 KiB
  __shared__ unsigned short Bs[4][256 * 32];   // 4 x 16 KiB  (128 KiB total)
  const int t = threadIdx.x;
  const int l = t & 63, w = t >> 6;            // 8 waves
  const int wr = w >> 2, wc = w & 3;           // 2M x 4N wave grid
  const int bid0 = blockIdx.y * NCB + blockIdx.x;
  const int swz = (bid0 & 7) * (NCB * 8) + (bid0 >> 3);   // bijective, nwg%8==0
  const int m0 = (swz / NCB) * 256, n0 = (swz % NCB) * 256;
  const int lr = l & 15;
  const int lkx = (((l >> 4) ^ ((l >> 1) & 3))) * 8;   // swizzled chunk (shorts)
  constexpr int kt = K >> 5;

  auto stage = [&](int buf, int ks) {
#pragma unroll
    for (int j = 0; j < 2; ++j) {
      const int idx = j * 512 + t;
      const int row = idx >> 2, qc = idx & 3;  // 256 rows x 4 chunks of 8 shorts
      const int qcx = qc ^ ((row >> 1) & 3);   // pre-swizzled global chunk
      gload_lds16(A + (size_t)(m0 + row) * K + ks + qcx * 8, &As[buf][idx * 8]);
      gload_lds16(B + (size_t)(n0 + row) * K + ks + qcx * 8, &Bs[buf][idx * 8]);
    }
  };

  short8 fa[2][8], fb[2][4];
  auto readfrags = [&](int set, int buf) {
#pragma unroll
    for (int mi = 0; mi < 8; ++mi)
      fa[set][mi] = *(const short8*)&As[buf][(wr * 128 + mi * 16 + lr) * 32 + lkx];
#pragma unroll
    for (int ni = 0; ni < 4; ++ni)
      fb[set][ni] = *(const short8*)&Bs[buf][(wc * 64 + ni * 16 + lr) * 32 + lkx];
  };

  floatx4 acc[8][4] = {};
  stage(0, 0);
  stage(1, 32);
  asm volatile("s_waitcnt vmcnt(4)" ::: "memory");   // tile 0 landed
  __builtin_amdgcn_s_barrier();
  __builtin_amdgcn_sched_barrier(0);
  readfrags(0, 0);

#pragma unroll 2
  for (int s = 0; s < kt; ++s) {
    const int cur = s & 1;
    if (s + 2 < kt) stage((s + 2) & 3, (s + 2) << 5);
    if (s + 1 < kt) {
      if (s + 2 < kt) {
        asm volatile("s_waitcnt vmcnt(4)" ::: "memory");  // tile s+1 landed
      } else {
        asm volatile("s_waitcnt vmcnt(0)" ::: "memory");
      }
      __builtin_amdgcn_s_barrier();                       // visible to all waves
      __builtin_amdgcn_sched_barrier(0);
      readfrags(cur ^ 1, (s + 1) & 3);
      __builtin_amdgcn_sched_barrier(0);                  // pin reads above MFMAs
    }
    __builtin_amdgcn_s_setprio(1);
#pragma unroll
    for (int mi = 0; mi < 8; ++mi)
#pragma unroll
      for (int ni = 0; ni < 4; ++ni)
        acc[mi][ni] = MFMA16(fa[cur][mi], fb[cur][ni], acc[mi][ni]);
    __builtin_amdgcn_s_setprio(0);
  }
#pragma unroll
  for (int mi = 0; mi < 8; ++mi)
#pragma unroll
    for (int ni = 0; ni < 4; ++ni)
#pragma unroll
      for (int i = 0; i < 4; ++i) {
        const int row = m0 + wr * 128 + mi * 16 + (l >> 4) * 4 + i;
        const int coff = wc * 64 + ni * 16 + lr;
        if (EPI == 0) {
          C[(size_t)row * DIM + n0 + coff] = acc[mi][ni][i] + bias[n0 + coff];
        } else {
          const int sel = n0 >> 10;                       // uniform per block
          unsigned short* dst = (sel == 0) ? qb : (sel == 1 ? kb : vb);
          dst[(size_t)row * DIM + (n0 & 1023) + coff] = f2b(acc[mi][ni][i]);
        }
      }
}

// Per-bucket MFMA: now stores S TRANSPOSED: S_T[e][d] = sum_p v[p][e]*psi[p][d]
// (A/B operands swapped vs r16 — A=v rows e, B=psi cols d). scan_all is
// layout-agnostic (cumsum over u, stride 4096); attn_out consumes S_T so its
// MFMA B-operand has contraction dim d row-contiguous.
__global__ __launch_bounds__(256) void bucket_stats(
    const unsigned short* __restrict__ kb, const unsigned short* __restrict__ vb,
    __half* __restrict__ S, float* __restrict__ ksum)
{
  const int bid = blockIdx.x;           // bh*128 + u
  const int u = bid & 127, bh = bid >> 7;
  const int b = bh >> 4, h = bh & 15;
  const int t = threadIdx.x, l = t & 63, w = t >> 6;
  __shared__ unsigned short kT[64][72];  // psi(k) bf16, [d][p]
  __shared__ unsigned short vT[64][72];  // v bf16, [e][p]
  const size_t rowbase = ((size_t)b * SEQ + (size_t)u * 64) * DIM + h * 64;
  {
    const int p = t >> 2, d0 = (t & 3) * 16;
    const size_t r = rowbase + (size_t)p * DIM + d0;
    const short8 k0 = *(const short8*)&kb[r];
    const short8 k1 = *(const short8*)&kb[r + 8];
    const short8 v0 = *(const short8*)&vb[r];
    const short8 v1 = *(const short8*)&vb[r + 8];
#pragma unroll
    for (int j = 0; j < 8; ++j) {
      const float z0 = b2f((unsigned short)k0[j]) * QK_SCALE;
      const float z1 = b2f((unsigned short)k1[j]) * QK_SCALE;
      kT[d0 + j][p]     = f2b(z0 > 0.f ? z0 + 1.f : __expf(z0));
      kT[d0 + 8 + j][p] = f2b(z1 > 0.f ? z1 + 1.f : __expf(z1));
      vT[d0 + j][p]     = (unsigned short)v0[j];
      vT[d0 + 8 + j][p] = (unsigned short)v1[j];
    }
  }
  __syncthreads();
  const int lr = l & 15, lk = (l >> 4) * 8;
  const short8 a0 = *(const short8*)&vT[w * 16 + lr][lk];        // A = v (rows e)
  const short8 a1 = *(const short8*)&vT[w * 16 + lr][lk + 32];
  floatx4 acc[4] = {};
#pragma unroll
  for (int ni = 0; ni < 4; ++ni) {
    const short8 b0 = *(const short8*)&kT[ni * 16 + lr][lk];     // B = psi (cols d)
    const short8 b1 = *(const short8*)&kT[ni * 16 + lr][lk + 32];
    acc[ni] = MFMA16(a0, b0, acc[ni]);
    acc[ni] = MFMA16(a1, b1, acc[ni]);
  }
  const size_t sb = (size_t)bid * 4096;
#pragma unroll
  for (int ni = 0; ni < 4; ++ni)
#pragma unroll
    for (int i = 0; i < 4; ++i) {
      const int e = w * 16 + (l >> 4) * 4 + i;   // C/D: row=(lane>>4)*4+reg
      const int d = ni * 16 + lr;                // C/D: col=lane&15
      S[sb + e * 64 + d] = __float2half_rn(acc[ni][i]);   // S_T[e][d]
    }
  __syncthreads();
  if (t < 64) {
    float ssum = 0.f;
    for (int p = 0; p < 64; ++p) ssum += b2f(kT[t][p]);
    ksum[(size_t)bid * 64 + t] = ssum;
  }
}

// Fused cumsum over buckets (batch-8 loads in flight; bitwise-identical order).
__global__ void scan_all(__half* __restrict__ S, float* __restrict__ ks) {
  const int bid = blockIdx.x;
  if (bid < 512) {
    const int tid = bid * 256 + threadIdx.x;
    const int bh = tid >> 12, de = tid & 4095;
    __half* p = S + (size_t)bh * NBUCK * 4096 + de;
    float run = 0.f;
    for (int u0 = 0; u0 < NBUCK; u0 += 8) {
      __half v[8];
#pragma unroll
      for (int j = 0; j < 8; ++j) v[j] = p[(size_t)(u0 + j) * 4096];
#pragma unroll
      for (int j = 0; j < 8; ++j) {
        run += __half2float(v[j]);
        v[j] = __float2half_rn(run);
      }
#pragma unroll
      for (int j = 0; j < 8; ++j) p[(size_t)(u0 + j) * 4096] = v[j];
    }
  } else {
    const int tid = (bid - 512) * 256 + threadIdx.x;
    if (tid >= 2048) return;
    const int bh = tid >> 6, d = tid & 63;
    float* p = ks + (size_t)bh * NBUCK * 64 + d;
    float run = 0.f;
    for (int u0 = 0; u0 < NBUCK; u0 += 8) {
      float v[8];
#pragma unroll
      for (int j = 0; j < 8; ++j) v[j] = p[(u0 + j) * 64];
#pragma unroll
      for (int j = 0; j < 8; ++j) { run += v[j]; v[j] = run; }
#pragma unroll
      for (int j = 0; j < 8; ++j) p[(u0 + j) * 64] = v[j];
    }
  }
}

// Per bucket u: attn = softmax(q*scale) @ (Ccum[u-1]/(kcum[u-1]+eps)); u=0 -> 0.
// MFMA rewrite: attn[r][e] = sum_d qn[r][d]*ccT[e][d] via 8 MFMA/wave.
// qn (softmax result, bf16 [r][d]) and ccT (S_T fp16 -> bf16 [e][d]) both have
// contraction dim d row-contiguous. Replaces the 2.1GB-LDS VALU loop.
__global__ __launch_bounds__(256) void attn_out(
    const unsigned short* __restrict__ qb, const __half* __restrict__ S,
    const float* __restrict__ ks, unsigned short* __restrict__ ab)
{
  const int bid = blockIdx.x;
  const int u = bid & 127, bh = bid >> 7;
  const int b = bh >> 4, h = bh & 15;
  const int t = threadIdx.x, l = t & 63, w = t >> 6;
  if (u == 0) {
    const size_t orow = (size_t)b * SEQ + (size_t)w * 16;
#pragma unroll
    for (int i = 0; i < 16; ++i) ab[(orow + i) * DIM + h * 64 + l] = 0;
    return;
  }
  __shared__ unsigned short ccT[64][72];   // S_T bf16, [e][d]
  __shared__ unsigned short qn[64][72];    // softmax(q)*recip bf16, [r][d]
  __shared__ float recip[64];
  __shared__ float part[64][4];
  __shared__ float rowstat[64];
  const size_t sb = ((size_t)bh * NBUCK + (u - 1)) * 4096;
  const __half2* S2 = (const __half2*)(S + sb);
  for (int idx = t; idx < 2048; idx += 256) {
    const float2 v2 = __half22float2(S2[idx]);
    const int e = idx >> 5, d = (idx & 31) * 2;
    ccT[e][d] = f2b(v2.x);
    ccT[e][d + 1] = f2b(v2.y);
  }
  if (t < 64) recip[t] = 1.f / (ks[((size_t)bh * NBUCK + (u - 1)) * 64 + t] + 1e-6f);
  const int p = t >> 2, c = t & 3;
  const size_t qrow = ((size_t)b * SEQ + (size_t)u * 64 + p) * DIM + h * 64 + c * 16;
  float qv[16];
#pragma unroll
  for (int ii = 0; ii < 4; ++ii) {
    const ushort4 qq = *(const ushort4*)&qb[qrow + ii * 4];
    qv[ii * 4 + 0] = b2f(qq.x) * QK_SCALE;
    qv[ii * 4 + 1] = b2f(qq.y) * QK_SCALE;
    qv[ii * 4 + 2] = b2f(qq.z) * QK_SCALE;
    qv[ii * 4 + 3] = b2f(qq.w) * QK_SCALE;
  }
  float mx = qv[0];
#pragma unroll
  for (int i = 1; i < 16; ++i) mx = fmaxf(mx, qv[i]);
  part[p][c] = mx;
  __syncthreads();
  if (c == 0) rowstat[p] = fmaxf(fmaxf(part[p][0], part[p][1]), fmaxf(part[p][2], part[p][3]));
  __syncthreads();
  const float rm = rowstat[p];
  float sum = 0.f;
#pragma unroll
  for (int i = 0; i < 16; ++i) { qv[i] = __expf(qv[i] - rm); sum += qv[i]; }
  part[p][c] = sum;
  __syncthreads();
  if (c == 0) rowstat[p] = part[p][0] + part[p][1] + part[p][2] + part[p][3];
  __syncthreads();
  const float inv = 1.f / rowstat[p];
#pragma unroll
  for (int i = 0; i < 16; ++i)
    qn[p][c * 16 + i] = f2b(qv[i] * inv * recip[c * 16 + i]);
  __syncthreads();
  const int lr = l & 15, lk = (l >> 4) * 8;
  const short8 a0 = *(const short8*)&qn[w * 16 + lr][lk];
  const short8 a1 = *(const short8*)&qn[w * 16 + lr][lk + 32];
  floatx4 acc[4] = {};
#pragma unroll
  for (int ni = 0; ni < 4; ++ni) {
    const short8 b0 = *(const short8*)&ccT[ni * 16 + lr][lk];
    const short8 b1 = *(const short8*)&ccT[ni * 16 + lr][lk + 32];
    acc[ni] = MFMA16(a0, b0, acc[ni]);
    acc[ni] = MFMA16(a1, b1, acc[ni]);
  }
  const size_t orow = (size_t)b * SEQ + (size_t)u * 64;
#pragma unroll
  for (int ni = 0; ni < 4; ++ni)
#pragma unroll
    for (int i = 0; i < 4; ++i) {
      const int r = w * 16 + (l >> 4) * 4 + i;   // C/D: row=(lane>>4)*4+reg
      const int e = ni * 16 + lr;                // C/D: col=lane&15
      ab[(orow + r) * DIM + h * 64 + e] = f2b(acc[ni][i]);
    }
}

extern "C" void kernel_launch(void* const* d_in, const int* in_sizes, int n_in,
                              void* d_out, int out_size, void* d_ws, size_t ws_size,
                              hipStream_t stream) {
  const float* x  = (const float*)d_in[0];
  const float* Wq = (const float*)d_in[1];
  const float* Wk = (const float*)d_in[2];
  const float* Wv = (const float*)d_in[3];
  const float* Wo = (const float*)d_in[4];
  const float* bo = (const float*)d_in[5];
  float* out = (float*)d_out;

  char* ws = (char*)d_ws;
  size_t off = 0;
  auto carve = [&](size_t bytes) -> void* {
    void* pp = ws + off;
    off += (bytes + 255) & ~(size_t)255;
    return pp;
  };
  unsigned short* qb = (unsigned short*)carve((size_t)MROWS * DIM * 2);   // 32 MiB
  unsigned short* kb = (unsigned short*)carve((size_t)MROWS * DIM * 2);   // 32 MiB (ab overlays)
  unsigned short* vb = (unsigned short*)carve((size_t)MROWS * DIM * 2);   // 32 MiB
  unsigned short* wob = (unsigned short*)carve((size_t)DIM * DIM * 2);    // 2 MiB
  float* ksum = (float*)carve((size_t)32 * NBUCK * 64 * 4);               // 1 MiB
  // 64 MiB scratch: phase1 = xb(32) + wchi(6); phase2+ = S fp16 (32, overlay on xb)
  char* scratch = (char*)carve((size_t)32 * NBUCK * 4096 * 4);
  unsigned short* xb   = (unsigned short*)scratch;
  unsigned short* wchi = (unsigned short*)(scratch + (size_t)MROWS * DIM * 2);
  __half* S = (__half*)scratch;
  unsigned short* ab = kb;  // overlay (kb dead after bucket_stats)
  if (off > ws_size) {
    ws_sentinel<<<1, 1, 0, stream>>>(out, (float)ws_size);
    return;
  }

  prep<<<5120, 256, 0, stream>>>((const float4*)x, (const float4*)Wq, (const float4*)Wk,
                                 (const float4*)Wv, (const float4*)Wo,
                                 (ushort4*)xb, (ushort4*)wchi, (ushort4*)wob);
  gemm256<1, 12, DIM><<<dim3(12, 64), 512, 0, stream>>>(
      xb, wchi, qb, kb, vb, nullptr, nullptr);
  bucket_stats<<<4096, 256, 0, stream>>>(kb, vb, S, ksum);
  scan_all<<<520, 256, 0, stream>>>(S, ksum);
  attn_out<<<4096, 256, 0, stream>>>(qb, S, ksum, ab);
  gemm256<0, 4, DIM><<<dim3(4, 64), 512, 0, stream>>>(
      ab, wob, nullptr, nullptr, nullptr, out, bo);
}